// Round 2
// baseline (127.635 us; speedup 1.0000x reference)
//
#include <hip/hip_runtime.h>
#include <hip/hip_cooperative_groups.h>
#include <stdint.h>

typedef float  f32x4 __attribute__((ext_vector_type(4)));
typedef short  s16x8 __attribute__((ext_vector_type(8)));

constexpr int Kdim    = 1024;
constexpr int Cdim    = 16;
constexpr int NCHUNK  = 4;                 // grid = 64*4 = 256 = #CUs -> coop launch needs only 1 block/CU
constexpr int ROWS_CH = 256;               // rows per block
constexpr int TROWS   = 32;                // rows per LDS tile
constexpr int NTILE   = ROWS_CH / TROWS;   // 8
constexpr int RS      = Kdim + 8;          // bf16 row stride (2064B = 129*16B: aligned, rotates banks)

static __device__ __forceinline__ ushort f2bf(float f) {
  uint32_t u = __builtin_bit_cast(uint32_t, f);
  u += 0x7FFFu + ((u >> 16) & 1u);         // RNE
  return (ushort)(u >> 16);
}

// K0: prep — W_col -> bf16 [c][j]; W_row -> transposed fp32 [i][c]; zero s accumulator + barrier counter
__global__ __launch_bounds__(256) void k_prep(const float* __restrict__ Wr, const float* __restrict__ Wc,
                                              ushort* __restrict__ Wcb, float* __restrict__ Wrt,
                                              float* __restrict__ s_ws, int* __restrict__ bar) {
  int id = blockIdx.x * 256 + threadIdx.x;   // 0..16383
  int c = id >> 10, i = id & 1023;
  Wcb[id] = f2bf(Wc[id]);
  Wrt[i * Cdim + c] = Wr[id];
  if (id < 64 * Cdim) s_ws[id] = 0.f;
  if (id == 0) *bar = 0;
}

// K1: phase1 = one read of x: r-FMA into registers (kept!), col via MFMA -> col_ws.
// grid-wide sync (coop OR manual atomic barrier). phase2 = dot r-partials vs complete col, atomicAdd s.
__global__ __launch_bounds__(256) void k_coop(const float* __restrict__ x, const float* __restrict__ Wrt,
                                              const ushort* __restrict__ Wcb, float* __restrict__ col_ws,
                                              float* __restrict__ s_ws, const float* __restrict__ b_row,
                                              const float* __restrict__ b_col, int use_coop,
                                              int* __restrict__ bar) {
  __shared__ ushort x_l[TROWS * RS];        // 66,048 B bf16 tile
  __shared__ float  colp[2][4 * 64 * 4];    //  8,192 B MFMA partials (double-buffered)
  __shared__ float  wred[4 * Cdim];         //    256 B reduction scratch

  const int t    = threadIdx.x;
  const int lane = t & 63;
  const int w    = t >> 6;
  const int b    = blockIdx.x >> 2;
  const int ch   = blockIdx.x & 3;
  const int i0   = ch * ROWS_CH;
  const float* xb = x + (size_t)b * Kdim * Kdim;
  const float* xt = xb + 4 * t;

  float racc[Cdim][4];
  #pragma unroll
  for (int c = 0; c < Cdim; ++c) { racc[c][0] = racc[c][1] = racc[c][2] = racc[c][3] = 0.f; }

  auto proc_row = [&](int row, int grow, f32x4 v) {
    const float* wrr = Wrt + (size_t)grow * Cdim;   // 16 uniform floats -> s_load
    #pragma unroll
    for (int c = 0; c < Cdim; ++c) {
      const float wv = wrr[c];
      racc[c][0] = fmaf(wv, v.x, racc[c][0]);
      racc[c][1] = fmaf(wv, v.y, racc[c][1]);
      racc[c][2] = fmaf(wv, v.z, racc[c][2]);
      racc[c][3] = fmaf(wv, v.w, racc[c][3]);
    }
    ushort4 u4 = make_ushort4(f2bf(v.x), f2bf(v.y), f2bf(v.z), f2bf(v.w));
    *(ushort4*)&x_l[row * RS + 4 * t] = u4;
  };

  auto phase_c = [&](int p, int r0p) {      // combine K-halves, store col in [b][i][c]
    if (t < 128) {
      const int it = t >> 6;
      const int l  = t & 63;
      f32x4 va = *(const f32x4*)&colp[p][(it * 64 + l) * 4];
      f32x4 vb = *(const f32x4*)&colp[p][((it + 2) * 64 + l) * 4];
      const int c     = l & 15;
      const int rbase = r0p + it * 16 + ((l >> 4) << 2);
      float* dst = col_ws + ((size_t)b * Kdim + rbase) * Cdim + c;
      #pragma unroll
      for (int q = 0; q < 4; ++q) dst[q * Cdim] = va[q] + vb[q];
    }
  };

  // depth-4 register prefetch ring: 32 KB/CU in flight
  f32x4 pa0, pa1, pa2, pa3, pb0, pb1, pb2, pb3;
  pa0 = *(const f32x4*)(xt + (size_t)(i0 + 0) * Kdim);
  pa1 = *(const f32x4*)(xt + (size_t)(i0 + 1) * Kdim);
  pa2 = *(const f32x4*)(xt + (size_t)(i0 + 2) * Kdim);
  pa3 = *(const f32x4*)(xt + (size_t)(i0 + 3) * Kdim);

  for (int tl = 0; tl < NTILE; ++tl) {
    const int r0 = i0 + tl * TROWS;

    if (tl) phase_c((tl - 1) & 1, r0 - TROWS);   // prev tile's col store overlaps phase A

    // ---- phase A: stream 32 rows; pa/pb alternate; last prefetch targets next tile (spans phase B)
    for (int g = 0; g < 8; g += 2) {
      const int nr1 = r0 + (g + 1) * 4;
      pb0 = *(const f32x4*)(xt + (size_t)(nr1 + 0) * Kdim);
      pb1 = *(const f32x4*)(xt + (size_t)(nr1 + 1) * Kdim);
      pb2 = *(const f32x4*)(xt + (size_t)(nr1 + 2) * Kdim);
      pb3 = *(const f32x4*)(xt + (size_t)(nr1 + 3) * Kdim);
      proc_row(g * 4 + 0, r0 + g * 4 + 0, pa0);
      proc_row(g * 4 + 1, r0 + g * 4 + 1, pa1);
      proc_row(g * 4 + 2, r0 + g * 4 + 2, pa2);
      proc_row(g * 4 + 3, r0 + g * 4 + 3, pa3);
      const int nr2 = r0 + (g + 2) * 4;          // == r0+32 when g==6 -> next tile group 0
      if (g + 2 < 8 || tl + 1 < NTILE) {         // guards OOB at chunk end
        pa0 = *(const f32x4*)(xt + (size_t)(nr2 + 0) * Kdim);
        pa1 = *(const f32x4*)(xt + (size_t)(nr2 + 1) * Kdim);
        pa2 = *(const f32x4*)(xt + (size_t)(nr2 + 2) * Kdim);
        pa3 = *(const f32x4*)(xt + (size_t)(nr2 + 3) * Kdim);
      }
      proc_row(g * 4 + 4, nr1 + 0, pb0);
      proc_row(g * 4 + 5, nr1 + 1, pb1);
      proc_row(g * 4 + 6, nr1 + 2, pb2);
      proc_row(g * 4 + 7, nr1 + 3, pb3);
    }
    __syncthreads();

    // ---- phase B: col-direction MFMA. wave w: i-tile (w&1), K-half (w>>1).
    {
      const int it   = w & 1;
      const int kh   = w >> 1;
      const int arow = it * 16 + (lane & 15);
      const int kg   = lane >> 4;
      const ushort* brow = Wcb + (size_t)(lane & 15) * Kdim;
      f32x4 acc = {0.f, 0.f, 0.f, 0.f};
      #pragma unroll
      for (int s = 0; s < 16; ++s) {
        const int ks = kh * 16 + s;
        s16x8 a  = *(const s16x8*)&x_l[arow * RS + ks * 32 + kg * 8];
        s16x8 bb = *(const s16x8*)(brow + ks * 32 + kg * 8);
        acc = __builtin_amdgcn_mfma_f32_16x16x32_bf16(a, bb, acc, 0, 0, 0);
      }
      *(f32x4*)&colp[tl & 1][(w * 64 + lane) * 4] = acc;
    }
    __syncthreads();
  }
  phase_c((NTILE - 1) & 1, i0 + (NTILE - 1) * TROWS);

  // ---- grid-wide sync: col_ws complete
  __threadfence();
  if (use_coop) {
    cooperative_groups::this_grid().sync();
  } else {
    __syncthreads();
    if (t == 0) {
      __hip_atomic_fetch_add(bar, 1, __ATOMIC_ACQ_REL, __HIP_MEMORY_SCOPE_AGENT);
      while (__hip_atomic_load(bar, __ATOMIC_ACQUIRE, __HIP_MEMORY_SCOPE_AGENT) < (int)gridDim.x) {
        __builtin_amdgcn_s_sleep(2);
      }
    }
    __syncthreads();
  }

  // ---- phase 2: s_ch[c] = sum_k (R_ch[c][k] + br/4)(col[c][k] + bc); col is L2/L3-hot
  float brq[Cdim], bcv[Cdim];
  #pragma unroll
  for (int c = 0; c < Cdim; ++c) { brq[c] = b_row[c] * (1.f / NCHUNK); bcv[c] = b_col[c]; }

  const float* clp = col_ws + ((size_t)b * Kdim + 4 * t) * Cdim;   // [i=4t][c]
  float pv[Cdim];
  #pragma unroll
  for (int c = 0; c < Cdim; ++c) pv[c] = 0.f;
  #pragma unroll
  for (int q = 0; q < 4; ++q) {
    #pragma unroll
    for (int cg = 0; cg < 4; ++cg) {
      f32x4 cv = *(const f32x4*)(clp + q * Cdim + cg * 4);
      #pragma unroll
      for (int e = 0; e < 4; ++e) {
        const int c = cg * 4 + e;
        pv[c] = fmaf(racc[c][q] + brq[c], cv[e] + bcv[c], pv[c]);
      }
    }
  }
  #pragma unroll
  for (int c = 0; c < Cdim; ++c) {
    float v = pv[c];
    #pragma unroll
    for (int off = 32; off; off >>= 1) v += __shfl_xor(v, off);
    if (lane == 0) wred[w * Cdim + c] = v;
  }
  __syncthreads();
  if (t < Cdim) {
    float v = wred[t] + wred[Cdim + t] + wred[2 * Cdim + t] + wred[3 * Cdim + t];
    atomicAdd(&s_ws[b * Cdim + t], v);
  }
}

// K2: broadcast s to (64,16,1024)
__global__ __launch_bounds__(256) void k_bcast(const float* __restrict__ s_ws, float* __restrict__ out) {
  const float s = s_ws[blockIdx.x];
  f32x4 o = {s, s, s, s};
  *(f32x4*)(out + (size_t)blockIdx.x * Kdim + 4 * threadIdx.x) = o;
}

extern "C" void kernel_launch(void* const* d_in, const int* in_sizes, int n_in,
                              void* d_out, int out_size, void* d_ws, size_t ws_size,
                              hipStream_t stream) {
  const float* x  = (const float*)d_in[0];
  const float* Wr = (const float*)d_in[1];
  const float* br = (const float*)d_in[2];
  const float* Wc = (const float*)d_in[3];
  const float* bc = (const float*)d_in[4];
  float* out = (float*)d_out;

  char* ws = (char*)d_ws;
  float*  col_ws = (float*)ws;                                  // 64*1024*16*4 = 4,194,304 B
  float*  s_ws   = (float*)(ws + 4194304);                      // 64*16*4      =     4,096 B
  int*    bar    = (int*)  (ws + 4194304 + 4096);               // 64 B (padded)
  ushort* wcb    = (ushort*)(ws + 4194304 + 4096 + 64);         // 16*1024*2    =    32,768 B
  float*  wrt    = (float*)(ws + 4194304 + 4096 + 64 + 32768);  // 1024*16*4    =    65,536 B

  k_prep<<<64, 256, 0, stream>>>(Wr, Wc, wcb, wrt, s_ws, bar);

  int use_coop = 1;
  void* args[] = { (void*)&x, (void*)&wrt, (void*)&wcb, (void*)&col_ws,
                   (void*)&s_ws, (void*)&br, (void*)&bc, (void*)&use_coop, (void*)&bar };
  hipError_t e = hipLaunchCooperativeKernel(reinterpret_cast<const void*>(&k_coop),
                                            dim3(64 * NCHUNK), dim3(256), args, 0u, stream);
  if (e != hipSuccess) {
    (void)hipGetLastError();   // clear sticky error
    k_coop<<<64 * NCHUNK, 256, 0, stream>>>(x, wrt, wcb, col_ws, s_ws, br, bc, 0, bar);
  }

  k_bcast<<<1024, 256, 0, stream>>>(s_ws, out);
}

// Round 3
// 62.879 us; speedup vs baseline: 2.0298x; 2.0298x over previous
//
#include <hip/hip_runtime.h>
#include <stdint.h>

typedef float  f32x4 __attribute__((ext_vector_type(4)));
typedef short  s16x8 __attribute__((ext_vector_type(8)));

constexpr int Kdim    = 1024;
constexpr int Cdim    = 16;
constexpr int NCHUNK  = 8;                 // grid = 512 -> 2 blocks/CU (LDS 74.2KB x2 <= 160KB)
constexpr int ROWS_CH = 128;               // rows per block
constexpr int TROWS   = 32;                // rows per LDS tile
constexpr int NTILE   = ROWS_CH / TROWS;   // 4
constexpr int RS      = Kdim + 8;          // bf16 row stride (2064B = 129*16B: aligned, rotates banks)

static __device__ __forceinline__ ushort f2bf(float f) {
  uint32_t u = __builtin_bit_cast(uint32_t, f);
  u += 0x7FFFu + ((u >> 16) & 1u);         // RNE
  return (ushort)(u >> 16);
}
static __device__ __forceinline__ float bf2f(ushort u) {
  return __builtin_bit_cast(float, (uint32_t)u << 16);
}

// K0: prep — W_col -> bf16 [c][j]; W_row -> transposed fp32 [i][c]
__global__ __launch_bounds__(256) void k_prep(const float* __restrict__ Wr, const float* __restrict__ Wc,
                                              ushort* __restrict__ Wcb, float* __restrict__ Wrt) {
  int id = blockIdx.x * 256 + threadIdx.x;   // 0..16383
  int c = id >> 10, i = id & 1023;
  Wcb[id] = f2bf(Wc[id]);
  Wrt[i * Cdim + c] = Wr[id];
}

// K1: one read of x. r-direction on VALU (fp32 regs -> bf16 partials out), col via MFMA -> col_ws [b][c][i].
// 2 blocks/CU: one block's MFMA phase overlaps the other's streaming phase.
__global__ __launch_bounds__(256, 2) void k_main(const float* __restrict__ x, const float* __restrict__ Wrt,
                                                 const ushort* __restrict__ Wcb, ushort* __restrict__ r_bf,
                                                 float* __restrict__ col_ws) {
  __shared__ ushort x_l[TROWS * RS];        // 66,048 B bf16 tile
  __shared__ float  colp[2][4 * 64 * 4];    //  8,192 B MFMA partials (double-buffered)

  const int t    = threadIdx.x;
  const int lane = t & 63;
  const int w    = t >> 6;
  const int b    = blockIdx.x >> 3;
  const int ch   = blockIdx.x & 7;
  const int i0   = ch * ROWS_CH;
  const float* xb = x + (size_t)b * Kdim * Kdim;
  const float* xt = xb + 4 * t;

  float racc[Cdim][4];
  #pragma unroll
  for (int c = 0; c < Cdim; ++c) { racc[c][0] = racc[c][1] = racc[c][2] = racc[c][3] = 0.f; }

  auto proc_row = [&](int row, int grow, f32x4 v) {
    const float* wrr = Wrt + (size_t)grow * Cdim;   // 16 uniform floats -> s_load
    #pragma unroll
    for (int c = 0; c < Cdim; ++c) {
      const float wv = wrr[c];
      racc[c][0] = fmaf(wv, v.x, racc[c][0]);
      racc[c][1] = fmaf(wv, v.y, racc[c][1]);
      racc[c][2] = fmaf(wv, v.z, racc[c][2]);
      racc[c][3] = fmaf(wv, v.w, racc[c][3]);
    }
    ushort4 u4 = make_ushort4(f2bf(v.x), f2bf(v.y), f2bf(v.z), f2bf(v.w));
    *(ushort4*)&x_l[row * RS + 4 * t] = u4;
  };

  auto phase_c = [&](int p, int r0p) {      // combine K-halves, store col in [b][c][i] (contig f32x4 in i)
    if (t < 128) {
      const int it = t >> 6;
      const int l  = t & 63;
      f32x4 va = *(const f32x4*)&colp[p][(it * 64 + l) * 4];
      f32x4 vb = *(const f32x4*)&colp[p][((it + 2) * 64 + l) * 4];
      const int c     = l & 15;
      const int rbase = r0p + it * 16 + ((l >> 4) << 2);   // D row = (lane>>4)*4 + q
      f32x4 o = va + vb;
      *(f32x4*)(col_ws + ((size_t)(b * Cdim + c)) * Kdim + rbase) = o;
    }
  };

  // depth-8 register prefetch ring: 128 B/thread in flight -> 64 KB/CU at 2 blocks
  f32x4 pa0, pa1, pa2, pa3, pb0, pb1, pb2, pb3;
  pa0 = *(const f32x4*)(xt + (size_t)(i0 + 0) * Kdim);
  pa1 = *(const f32x4*)(xt + (size_t)(i0 + 1) * Kdim);
  pa2 = *(const f32x4*)(xt + (size_t)(i0 + 2) * Kdim);
  pa3 = *(const f32x4*)(xt + (size_t)(i0 + 3) * Kdim);

  for (int tl = 0; tl < NTILE; ++tl) {
    const int r0 = i0 + tl * TROWS;

    if (tl) phase_c((tl - 1) & 1, r0 - TROWS);   // prev tile's col store overlaps phase A

    // ---- phase A: stream 32 rows; pa/pb alternate; last prefetch targets next tile (spans phase B)
    for (int g = 0; g < 8; g += 2) {
      const int nr1 = r0 + (g + 1) * 4;
      pb0 = *(const f32x4*)(xt + (size_t)(nr1 + 0) * Kdim);
      pb1 = *(const f32x4*)(xt + (size_t)(nr1 + 1) * Kdim);
      pb2 = *(const f32x4*)(xt + (size_t)(nr1 + 2) * Kdim);
      pb3 = *(const f32x4*)(xt + (size_t)(nr1 + 3) * Kdim);
      proc_row(g * 4 + 0, r0 + g * 4 + 0, pa0);
      proc_row(g * 4 + 1, r0 + g * 4 + 1, pa1);
      proc_row(g * 4 + 2, r0 + g * 4 + 2, pa2);
      proc_row(g * 4 + 3, r0 + g * 4 + 3, pa3);
      const int nr2 = r0 + (g + 2) * 4;          // == r0+32 when g==6 -> next tile group 0
      if (g + 2 < 8 || tl + 1 < NTILE) {         // guards OOB read past chunk end
        pa0 = *(const f32x4*)(xt + (size_t)(nr2 + 0) * Kdim);
        pa1 = *(const f32x4*)(xt + (size_t)(nr2 + 1) * Kdim);
        pa2 = *(const f32x4*)(xt + (size_t)(nr2 + 2) * Kdim);
        pa3 = *(const f32x4*)(xt + (size_t)(nr2 + 3) * Kdim);
      }
      proc_row(g * 4 + 4, nr1 + 0, pb0);
      proc_row(g * 4 + 5, nr1 + 1, pb1);
      proc_row(g * 4 + 6, nr1 + 2, pb2);
      proc_row(g * 4 + 7, nr1 + 3, pb3);
    }
    __syncthreads();

    // ---- phase B: col-direction MFMA. wave w: i-tile (w&1), K-half (w>>1).
    {
      const int it   = w & 1;
      const int kh   = w >> 1;
      const int arow = it * 16 + (lane & 15);
      const int kg   = lane >> 4;
      const ushort* brow = Wcb + (size_t)(lane & 15) * Kdim;
      f32x4 acc = {0.f, 0.f, 0.f, 0.f};
      #pragma unroll
      for (int s = 0; s < 16; ++s) {
        const int ks = kh * 16 + s;
        s16x8 a  = *(const s16x8*)&x_l[arow * RS + ks * 32 + kg * 8];
        s16x8 bb = *(const s16x8*)(brow + ks * 32 + kg * 8);
        acc = __builtin_amdgcn_mfma_f32_16x16x32_bf16(a, bb, acc, 0, 0, 0);
      }
      *(f32x4*)&colp[tl & 1][(w * 64 + lane) * 4] = acc;
    }
    __syncthreads();
  }
  phase_c((NTILE - 1) & 1, i0 + (NTILE - 1) * TROWS);

  // ---- write r partials for this chunk as bf16: [b][ch][c][k], coalesced 8B stores
  ushort* rp = r_bf + ((size_t)(b * NCHUNK + ch) * Cdim) * Kdim + 4 * t;
  #pragma unroll
  for (int c = 0; c < Cdim; ++c) {
    ushort4 u4 = make_ushort4(f2bf(racc[c][0]), f2bf(racc[c][1]), f2bf(racc[c][2]), f2bf(racc[c][3]));
    *(ushort4*)(rp + (size_t)c * Kdim) = u4;
  }
}

// K2 (fused): per (b,c): r = sum of bf16 chunk partials; s = dot(r+br, col+bc); broadcast-write 1024 outputs
__global__ __launch_bounds__(256) void k_out(const ushort* __restrict__ r_bf, const float* __restrict__ col_ws,
                                             const float* __restrict__ b_row, const float* __restrict__ b_col,
                                             float* __restrict__ out) {
  const int bid = blockIdx.x;             // 0..1023
  const int b = bid >> 4, c = bid & 15;
  const int t = threadIdx.x;
  const float br = b_row[c], bc = b_col[c];

  f32x4 rv = {0.f, 0.f, 0.f, 0.f};
  #pragma unroll
  for (int ch = 0; ch < NCHUNK; ++ch) {
    ushort4 u = *(const ushort4*)(r_bf + ((size_t)(b * NCHUNK + ch) * Cdim + c) * Kdim + 4 * t);
    rv.x += bf2f(u.x); rv.y += bf2f(u.y); rv.z += bf2f(u.z); rv.w += bf2f(u.w);
  }
  f32x4 cv = *(const f32x4*)(col_ws + ((size_t)(b * Cdim + c)) * Kdim + 4 * t);
  float part = 0.f;
  #pragma unroll
  for (int q = 0; q < 4; ++q) part += (rv[q] + br) * (cv[q] + bc);

  #pragma unroll
  for (int off = 1; off < 64; off <<= 1) part += __shfl_xor(part, off);
  __shared__ float wsum[4];
  if ((t & 63) == 0) wsum[t >> 6] = part;
  __syncthreads();
  const float s = wsum[0] + wsum[1] + wsum[2] + wsum[3];

  f32x4 o = {s, s, s, s};
  *(f32x4*)(out + ((size_t)(b * Cdim + c)) * Kdim + 4 * t) = o;
}

extern "C" void kernel_launch(void* const* d_in, const int* in_sizes, int n_in,
                              void* d_out, int out_size, void* d_ws, size_t ws_size,
                              hipStream_t stream) {
  const float* x  = (const float*)d_in[0];
  const float* Wr = (const float*)d_in[1];
  const float* br = (const float*)d_in[2];
  const float* Wc = (const float*)d_in[3];
  const float* bc = (const float*)d_in[4];
  float* out = (float*)d_out;

  char* ws = (char*)d_ws;
  ushort* r_bf   = (ushort*)ws;                                  // 64*8*16*1024*2 = 16,777,216 B
  float*  col_ws = (float*)(ws + 16777216);                      // 64*16*1024*4   =  4,194,304 B
  ushort* wcb    = (ushort*)(ws + 16777216 + 4194304);           // 16*1024*2      =     32,768 B
  float*  wrt    = (float*)(ws + 16777216 + 4194304 + 32768);    // 1024*16*4      =     65,536 B

  k_prep<<<64, 256, 0, stream>>>(Wr, Wc, wcb, wrt);
  k_main<<<512, 256, 0, stream>>>(x, wrt, wcb, r_bf, col_ws);
  k_out<<<1024, 256, 0, stream>>>(r_bf, col_ws, br, bc, out);
}